// Round 6
// baseline (171.701 us; speedup 1.0000x reference)
//
#include <hip/hip_runtime.h>

// GCN 2-layer. out = tanh((Â x) W1 + b1) W2 + b2, with Â(xW1)=(Âx)W1.
// Round 17: UNIFORM gather. col[node] fixed at 16 slots (sentinel-padded);
// agg gather is straight-line 2x8 rows, no divergent loop (was max-of-4
// Poisson ceil(deg/8) per wave = ~20-25% wasted slots). Edges beyond 16
// (E~14K) spill at compaction into per-agg-block overflow lists, drained by
// a short broadcast scan in agg. col shrinks 9.6->3.2MB.
//  k_scatter8: partition p=blockIdx&7 (~XCD) -> cnt8[p][N], col8[p][N][16]
//    (XCD-local L2, no dirty-line bounce) + W frag swizzle.
//  k_prep: (i<8N) compact col8 -> col[node][16] via shfl prefix; idx>=16 ->
//    ovfbuf[node/32]; lane7: cnt[node]=raw degree + sentinel pad to 16.
//    (i<32N) xb = bf16(x * dinv) (raw degree via shfl) + zero row xb[n].
//  k_agg_gemm: straight-line 16-row gather + ovf scan + GEMM1(+bias+tanh)
//    + GEMM2(+bias).
// 4 graph nodes: memset(cnt8+ovfcnt) | scatter8 | prep | agg.
// ws: cnt8(1.6MB)+ovfcnt | cnt(0.2) | col8(25.6) | col(3.2) | ovfb(0.8)
//     | xb(12.8) | w1f | w2f

#define DFEAT 128
#define CAP8 16     // per-partition scatter capacity (lambda=1.6, P(ovf)~1e-12)
#define NPART 8
#define CAPC 16     // fixed per-node col capacity (fed to uniform gather)
#define BROWS 32    // nodes per agg block
#define OVFCAP 64   // per-agg-block overflow capacity (~9 expected, +8.9 sigma)

typedef __attribute__((ext_vector_type(8))) short short8;
typedef __attribute__((ext_vector_type(4))) float float4v;

__device__ __forceinline__ float bflo(unsigned int u) {
    union { unsigned int i; float f; } v; v.i = u << 16; return v.f;
}
__device__ __forceinline__ float bfhi(unsigned int u) {
    union { unsigned int i; float f; } v; v.i = u & 0xffff0000u; return v.f;
}
__device__ __forceinline__ unsigned short f2bf(float f) {
    union { unsigned int i; float f; } v; v.f = f;
    unsigned int r = v.i + 0x7fffu + ((v.i >> 16) & 1u);  // RNE
    return (unsigned short)(r >> 16);
}
__device__ __forceinline__ unsigned int pack2(float a, float b) {
    return (unsigned int)f2bf(a) | ((unsigned int)f2bf(b) << 16);
}
// tanh(x) = 1 - 2/(exp(2x)+1); exact at +-inf.
__device__ __forceinline__ float fast_tanh(float x) {
    float e = __expf(2.0f * x);
    float r = __builtin_amdgcn_rcpf(e + 1.0f);  // raw v_rcp_f32, ~1 ulp
    return __builtin_fmaf(-2.0f, r, 1.0f);
}

// Partitioned count+scatter (+ W frag swizzle). Block b writes only
// partition b&7: cnt8[p*n+d], col8[(p*n+d)*CAP8 + slot].
__global__ void k_scatter8(const int* __restrict__ src, const int* __restrict__ dst,
                           int* __restrict__ cnt8, int* __restrict__ col8,
                           const float* __restrict__ W1, const float* __restrict__ W2,
                           unsigned short* __restrict__ w1f, unsigned short* __restrict__ w2f,
                           int e, int n) {
    int i = blockIdx.x * blockDim.x + threadIdx.x;
    if (i < 2 * DFEAT * DFEAT) {  // W fragment swizzle (B-operand layout)
        int which = i >> 14;
        int idx = i & 16383;
        int k = idx >> 7, nn = idx & 127;
        int f = ((nn >> 4) << 2) + (k >> 5);
        int lane = (nn & 15) | (((k >> 3) & 3) << 4);
        int j = k & 7;
        int o = f * 512 + lane * 8 + j;
        if (which == 0) w1f[o] = f2bf(W1[idx]);
        else            w2f[o] = f2bf(W2[idx]);
    }
    if (i < e) {
        int p = blockIdx.x & (NPART - 1);  // ~XCD id (perf-only assumption)
        int d = dst[i];
        int cell = p * n + d;
        int q = atomicAdd(&cnt8[cell], 1);
        if (q < CAP8) col8[(size_t)cell * CAP8 + q] = src[i];
    }
}

// Parallel compaction + conversion.
//  i < 8N : thread (node,p) copies its partition bucket into col[node][16]
//           at the shfl-prefix offset; entries at idx>=16 spill to the node's
//           agg-block overflow list. lane7: cnt[node]=raw deg, sentinel-pad.
//  i < 32N: xb = bf16(x * dinv); raw degree via shfl_xor sum of cnt8.
//  i in [32N, 32N+32): zero row xb[n] (sentinel rows contribute 0).
__global__ void k_prep(const float* __restrict__ x, const int* __restrict__ cnt8,
                       int* __restrict__ cnt, const int* __restrict__ col8,
                       int* __restrict__ col, int* __restrict__ ovfcnt,
                       int2* __restrict__ ovfb,
                       unsigned int* __restrict__ xb2, int n) {
    int i = blockIdx.x * blockDim.x + threadIdx.x;
    const int n32 = n * 32;
    if (i < n * NPART) {  // compaction (8-lane groups, never straddle warp)
        int node = i >> 3, p = i & 7;
        int cell = p * n + node;
        int rawc = cnt8[cell];
        int c = min(rawc, CAP8);
        int pre = c;  // inclusive scan of clamped counts over the 8-lane group
        #pragma unroll
        for (int d = 1; d < 8; d <<= 1) {
            int v = __shfl_up(pre, d, 8);
            if (p >= d) pre += v;
        }
        int prefix = pre - c;
        int rawtot = rawc;  // raw degree (for dinv; includes spilled edges)
        rawtot += __shfl_xor(rawtot, 1, 8);
        rawtot += __shfl_xor(rawtot, 2, 8);
        rawtot += __shfl_xor(rawtot, 4, 8);
        const int* bp = col8 + (size_t)cell * CAP8;
        int* cw = col + (size_t)node * CAPC;
        for (int j = 0; j < c; ++j) {
            int idx = prefix + j;
            if (idx < CAPC) {
                cw[idx] = bp[j];
            } else {  // spill to the agg block's overflow list (~14K edges total)
                int b = node >> 5;  // BROWS = 32
                int j2 = atomicAdd(&ovfcnt[b], 1);
                if (j2 < OVFCAP) ovfb[b * OVFCAP + j2] = make_int2(node, bp[j]);
            }
        }
        if (p == 7) {
            cnt[node] = rawtot;
            int k = min(pre, CAPC);
            for (; k < CAPC; ++k) cw[k] = n;  // sentinel pad to exactly 16
        }
    }
    if (i < n32) {  // conversion: 4 floats/thread, 32 threads/node
        int node = i >> 5;
        int q = i & 7;
        int deg = cnt8[q * n + node];  // raw, 8-way redundant, coalesced
        deg += __shfl_xor(deg, 1, 8);
        deg += __shfl_xor(deg, 2, 8);
        deg += __shfl_xor(deg, 4, 8);
        float di = rsqrtf((float)(deg + 1));  // +1 self-loop
        float4 v = ((const float4*)x)[i];
        xb2[i * 2]     = pack2(v.x * di, v.y * di);
        xb2[i * 2 + 1] = pack2(v.z * di, v.w * di);
    } else if (i < n32 + 32) {  // zero row xb[n]
        xb2[i * 2] = 0u;
        xb2[i * 2 + 1] = 0u;
    }
}

// Fused: per-block aggregation of BROWS nodes into LDS, then
// GEMM1(+bias+tanh) -> LDS -> GEMM2(+bias) -> fp32 out.
// Gather: 2 passes x (16 nodes x 16 lanes); STRAIGHT-LINE 16 rows per node
// (2 x 8-deep), sentinel rows hit the L1-hot zero row; then a short
// broadcast scan of the block's overflow list (~9 entries).
// GEMM: wave w = (strip=w>>1) x (colh=w&1); A[m=lane&15][k=(lane>>4)*8+j];
// D: col=lane&15, row=(lane>>4)*4+reg (m89-verified layouts).
__global__ __launch_bounds__(256) void k_agg_gemm(
    const uint4* __restrict__ xb4, const int* __restrict__ cnt,
    const int* __restrict__ col, const int* __restrict__ ovfcnt,
    const int2* __restrict__ ovfb,
    const unsigned short* __restrict__ w1f, const float* __restrict__ b1,
    const unsigned short* __restrict__ w2f, const float* __restrict__ b2,
    float* __restrict__ out, int n) {
    __shared__ unsigned short aggs[BROWS * 136];  // 8.7 KB, 136-pitch
    __shared__ unsigned short hs[BROWS * 136];    // 8.7 KB
    const int t = threadIdx.x;

    // ---- aggregation phase ----
    const int lane16 = t & 15;
    const int sub = t >> 4;  // 0..15
    const int bcnt = min(ovfcnt[blockIdx.x], OVFCAP);
    for (int g = 0; g < BROWS / 16; ++g) {
        int node_local = g * 16 + sub;
        int node = blockIdx.x * BROWS + node_local;
        int nodec = min(node, n - 1);
        int raw = cnt[nodec];
        float di = rsqrtf((float)(raw + 1));  // bitwise-matches prep's dinv
        uint4 v = xb4[(size_t)nodec * 16 + lane16];  // self term (dinv folded)
        float a0 = bflo(v.x), a1 = bfhi(v.x), a2 = bflo(v.y), a3 = bfhi(v.y);
        float a4 = bflo(v.z), a5 = bfhi(v.z), a6 = bflo(v.w), a7 = bfhi(v.w);
        const int4* col4 = (const int4*)(col + (size_t)nodec * CAPC);
        {   // rows 0..7
            int4 sa = col4[0];
            int4 sb = col4[1];
            uint4 u0 = xb4[(size_t)sa.x * 16 + lane16];
            uint4 u1 = xb4[(size_t)sa.y * 16 + lane16];
            uint4 u2 = xb4[(size_t)sa.z * 16 + lane16];
            uint4 u3 = xb4[(size_t)sa.w * 16 + lane16];
            uint4 u4 = xb4[(size_t)sb.x * 16 + lane16];
            uint4 u5 = xb4[(size_t)sb.y * 16 + lane16];
            uint4 u6 = xb4[(size_t)sb.z * 16 + lane16];
            uint4 u7 = xb4[(size_t)sb.w * 16 + lane16];
            a0 += bflo(u0.x); a1 += bfhi(u0.x); a2 += bflo(u0.y); a3 += bfhi(u0.y);
            a4 += bflo(u0.z); a5 += bfhi(u0.z); a6 += bflo(u0.w); a7 += bfhi(u0.w);
            a0 += bflo(u1.x); a1 += bfhi(u1.x); a2 += bflo(u1.y); a3 += bfhi(u1.y);
            a4 += bflo(u1.z); a5 += bfhi(u1.z); a6 += bflo(u1.w); a7 += bfhi(u1.w);
            a0 += bflo(u2.x); a1 += bfhi(u2.x); a2 += bflo(u2.y); a3 += bfhi(u2.y);
            a4 += bflo(u2.z); a5 += bfhi(u2.z); a6 += bflo(u2.w); a7 += bfhi(u2.w);
            a0 += bflo(u3.x); a1 += bfhi(u3.x); a2 += bflo(u3.y); a3 += bfhi(u3.y);
            a4 += bflo(u3.z); a5 += bfhi(u3.z); a6 += bflo(u3.w); a7 += bfhi(u3.w);
            a0 += bflo(u4.x); a1 += bfhi(u4.x); a2 += bflo(u4.y); a3 += bfhi(u4.y);
            a4 += bflo(u4.z); a5 += bfhi(u4.z); a6 += bflo(u4.w); a7 += bfhi(u4.w);
            a0 += bflo(u5.x); a1 += bfhi(u5.x); a2 += bflo(u5.y); a3 += bfhi(u5.y);
            a4 += bflo(u5.z); a5 += bfhi(u5.z); a6 += bflo(u5.w); a7 += bfhi(u5.w);
            a0 += bflo(u6.x); a1 += bfhi(u6.x); a2 += bflo(u6.y); a3 += bfhi(u6.y);
            a4 += bflo(u6.z); a5 += bfhi(u6.z); a6 += bflo(u6.w); a7 += bfhi(u6.w);
            a0 += bflo(u7.x); a1 += bfhi(u7.x); a2 += bflo(u7.y); a3 += bfhi(u7.y);
            a4 += bflo(u7.z); a5 += bfhi(u7.z); a6 += bflo(u7.w); a7 += bfhi(u7.w);
        }
        {   // rows 8..15
            int4 sa = col4[2];
            int4 sb = col4[3];
            uint4 u0 = xb4[(size_t)sa.x * 16 + lane16];
            uint4 u1 = xb4[(size_t)sa.y * 16 + lane16];
            uint4 u2 = xb4[(size_t)sa.z * 16 + lane16];
            uint4 u3 = xb4[(size_t)sa.w * 16 + lane16];
            uint4 u4 = xb4[(size_t)sb.x * 16 + lane16];
            uint4 u5 = xb4[(size_t)sb.y * 16 + lane16];
            uint4 u6 = xb4[(size_t)sb.z * 16 + lane16];
            uint4 u7 = xb4[(size_t)sb.w * 16 + lane16];
            a0 += bflo(u0.x); a1 += bfhi(u0.x); a2 += bflo(u0.y); a3 += bfhi(u0.y);
            a4 += bflo(u0.z); a5 += bfhi(u0.z); a6 += bflo(u0.w); a7 += bfhi(u0.w);
            a0 += bflo(u1.x); a1 += bfhi(u1.x); a2 += bflo(u1.y); a3 += bfhi(u1.y);
            a4 += bflo(u1.z); a5 += bfhi(u1.z); a6 += bflo(u1.w); a7 += bfhi(u1.w);
            a0 += bflo(u2.x); a1 += bfhi(u2.x); a2 += bflo(u2.y); a3 += bfhi(u2.y);
            a4 += bflo(u2.z); a5 += bfhi(u2.z); a6 += bflo(u2.w); a7 += bfhi(u2.w);
            a0 += bflo(u3.x); a1 += bfhi(u3.x); a2 += bflo(u3.y); a3 += bfhi(u3.y);
            a4 += bflo(u3.z); a5 += bfhi(u3.z); a6 += bflo(u3.w); a7 += bfhi(u3.w);
            a0 += bflo(u4.x); a1 += bfhi(u4.x); a2 += bflo(u4.y); a3 += bfhi(u4.y);
            a4 += bflo(u4.z); a5 += bfhi(u4.z); a6 += bflo(u4.w); a7 += bfhi(u4.w);
            a0 += bflo(u5.x); a1 += bfhi(u5.x); a2 += bflo(u5.y); a3 += bfhi(u5.y);
            a4 += bflo(u5.z); a5 += bfhi(u5.z); a6 += bflo(u5.w); a7 += bfhi(u5.w);
            a0 += bflo(u6.x); a1 += bfhi(u6.x); a2 += bflo(u6.y); a3 += bfhi(u6.y);
            a4 += bflo(u6.z); a5 += bfhi(u6.z); a6 += bflo(u6.w); a7 += bfhi(u6.w);
            a0 += bflo(u7.x); a1 += bfhi(u7.x); a2 += bflo(u7.y); a3 += bfhi(u7.y);
            a4 += bflo(u7.z); a5 += bfhi(u7.z); a6 += bflo(u7.w); a7 += bfhi(u7.w);
        }
        // overflow scan (~9 entries/block): only the matching group gathers.
        for (int j = 0; j < bcnt; ++j) {
            int2 ov = ovfb[blockIdx.x * OVFCAP + j];
            if (ov.x == node) {  // node unclamped: padding groups never match
                uint4 u = xb4[(size_t)ov.y * 16 + lane16];
                a0 += bflo(u.x); a1 += bfhi(u.x); a2 += bflo(u.y); a3 += bfhi(u.y);
                a4 += bflo(u.z); a5 += bfhi(u.z); a6 += bflo(u.w); a7 += bfhi(u.w);
            }
        }
        uint4 o;
        o.x = pack2(a0 * di, a1 * di);
        o.y = pack2(a2 * di, a3 * di);
        o.z = pack2(a4 * di, a5 * di);
        o.w = pack2(a6 * di, a7 * di);
        *(uint4*)&aggs[node_local * 136 + lane16 * 8] = o;  // 16 B LDS store
    }
    __syncthreads();

    // ---- GEMM phase: wave -> (row strip, col half) ----
    const int wave = t >> 6, l = t & 63;
    const int strip = wave >> 1;   // 0/1: rows strip*16 .. +15
    const int colh = wave & 1;     // 0/1: cols colh*64 .. +63
    const int kq = l >> 4;
    const int lc = l & 15;
    const int row_local = strip * 16 + lc;

    float4v acc[4];
    for (int ct = 0; ct < 4; ++ct) acc[ct] = (float4v){0.f, 0.f, 0.f, 0.f};
    for (int kc = 0; kc < 4; ++kc) {
        short8 a = *(const short8*)(aggs + row_local * 136 + kc * 32 + kq * 8);
        for (int ct = 0; ct < 4; ++ct) {
            int ctg = colh * 4 + ct;
            short8 b = *(const short8*)(w1f + (ctg * 4 + kc) * 512 + l * 8);
            acc[ct] = __builtin_amdgcn_mfma_f32_16x16x32_bf16(a, b, acc[ct], 0, 0, 0);
        }
    }
    const int drow0 = strip * 16 + kq * 4;
    for (int ct = 0; ct < 4; ++ct) {
        int c = colh * 64 + ct * 16 + lc;
        float bb = b1[c];
        for (int r = 0; r < 4; ++r) {
            float v = fast_tanh(acc[ct][r] + bb);
            hs[(drow0 + r) * 136 + c] = f2bf(v);
        }
    }
    __syncthreads();

    float4v acc2[4];
    for (int ct = 0; ct < 4; ++ct) acc2[ct] = (float4v){0.f, 0.f, 0.f, 0.f};
    for (int kc = 0; kc < 4; ++kc) {
        short8 a = *(const short8*)(hs + row_local * 136 + kc * 32 + kq * 8);
        for (int ct = 0; ct < 4; ++ct) {
            int ctg = colh * 4 + ct;
            short8 b = *(const short8*)(w2f + (ctg * 4 + kc) * 512 + l * 8);
            acc2[ct] = __builtin_amdgcn_mfma_f32_16x16x32_bf16(a, b, acc2[ct], 0, 0, 0);
        }
    }
    const int orow0 = blockIdx.x * BROWS + drow0;
    for (int ct = 0; ct < 4; ++ct) {
        int c = colh * 64 + ct * 16 + lc;
        float bb = b2[c];
        for (int r = 0; r < 4; ++r) {
            int orow = orow0 + r;
            if (orow < n) out[(size_t)orow * DFEAT + c] = acc2[ct][r] + bb;
        }
    }
}

static inline size_t align256(size_t v) { return (v + 255) & ~(size_t)255; }

extern "C" void kernel_launch(void* const* d_in, const int* in_sizes, int n_in,
                              void* d_out, int out_size, void* d_ws, size_t ws_size,
                              hipStream_t stream) {
    const float* x  = (const float*)d_in[0];
    const int*   ei = (const int*)d_in[1];
    const float* W1 = (const float*)d_in[2];
    const float* b1 = (const float*)d_in[3];
    const float* W2 = (const float*)d_in[4];
    const float* b2 = (const float*)d_in[5];
    float* out = (float*)d_out;

    const int N = in_sizes[0] / DFEAT;   // 50000
    const int E = in_sizes[1] / 2;       // 640000
    const int* src = ei;
    const int* dst = ei + E;
    const int nblk = (N + BROWS - 1) / BROWS;

    char* ws = (char*)d_ws;
    size_t off = 0;
    int* cnt8 = (int*)(ws + off); off += (size_t)NPART * N * 4;        // 256-aligned
    int* ovfc = (int*)(ws + off); off = align256(off + (size_t)nblk * 4);
    int* cnt  = (int*)(ws + off); off += align256((size_t)N * 4);
    int* col8 = (int*)(ws + off); off += align256((size_t)NPART * N * CAP8 * 4);
    int* col  = (int*)(ws + off); off += align256((size_t)N * CAPC * 4);
    int2* ovfb = (int2*)(ws + off); off += align256((size_t)nblk * OVFCAP * 8);
    unsigned short* xb  = (unsigned short*)(ws + off); off += align256((size_t)(N + 1) * DFEAT * 2);
    unsigned short* w1f = (unsigned short*)(ws + off); off += align256((size_t)DFEAT * DFEAT * 2);
    unsigned short* w2f = (unsigned short*)(ws + off); off += align256((size_t)DFEAT * DFEAT * 2);

    int t1 = E > 2 * DFEAT * DFEAT ? E : 2 * DFEAT * DFEAT;
    int t2 = N * 32 + 32;  // covers compaction (8N), conversion (32N), zero row

    hipMemsetAsync(cnt8, 0, (size_t)NPART * N * 4 + (size_t)nblk * 4, stream);
    k_scatter8<<<(t1 + 255) / 256, 256, 0, stream>>>(
        src, dst, cnt8, col8, W1, W2, w1f, w2f, E, N);
    k_prep<<<(t2 + 255) / 256, 256, 0, stream>>>(
        x, cnt8, cnt, col8, col, ovfc, ovfb, (unsigned int*)xb, N);
    k_agg_gemm<<<nblk, 256, 0, stream>>>(
        (const uint4*)xb, cnt, col, ovfc, ovfb, w1f, b1, w2f, b2, out, N);
}

// Round 7
// 162.279 us; speedup vs baseline: 1.0581x; 1.0581x over previous
//
#include <hip/hip_runtime.h>

// GCN 2-layer. out = tanh((Â x) W1 + b1) W2 + b2, with Â(xW1)=(Âx)W1.
// Round 18: R11 (best, 161.7us) + two surgical deltas:
//  (1) cnt stride-16: one 64B line per node counter -> kills same-line atomic
//      RMW serialization in count_scatter (was 205 atomics/line on 3125 lines).
//  (2) agg: 2-quad (8-deep) gather unroll + mult-8 sentinel padding (R16-
//      measured 44.2us / 40 VGPR variant).
// Everything else identical to R11. 4 nodes: memset | count_scatter(+W) |
// prep(dinv-fold conv + pad) | agg_gemm.
// ws: cnt(3.2MB strided) | col(9.6MB) | xb(12.8MB,+1 zero row) | w1f | w2f

#define DFEAT 128
#define CAP 48       // bucket capacity per node (mult of 8, int4-aligned)
#define CSTR 16      // cnt stride in ints (64 B = one line per node)
#define BROWS 32     // nodes per block

typedef __attribute__((ext_vector_type(8))) short short8;
typedef __attribute__((ext_vector_type(4))) float float4v;

__device__ __forceinline__ float bflo(unsigned int u) {
    union { unsigned int i; float f; } v; v.i = u << 16; return v.f;
}
__device__ __forceinline__ float bfhi(unsigned int u) {
    union { unsigned int i; float f; } v; v.i = u & 0xffff0000u; return v.f;
}
__device__ __forceinline__ unsigned short f2bf(float f) {
    union { unsigned int i; float f; } v; v.f = f;
    unsigned int r = v.i + 0x7fffu + ((v.i >> 16) & 1u);  // RNE
    return (unsigned short)(r >> 16);
}
__device__ __forceinline__ unsigned int pack2(float a, float b) {
    return (unsigned int)f2bf(a) | ((unsigned int)f2bf(b) << 16);
}
// tanh(x) = 1 - 2/(exp(2x)+1); exact at +-inf.
__device__ __forceinline__ float fast_tanh(float x) {
    float e = __expf(2.0f * x);
    float r = __builtin_amdgcn_rcpf(e + 1.0f);  // raw v_rcp_f32, ~1 ulp
    return __builtin_fmaf(-2.0f, r, 1.0f);
}

// One pass: in-degree count (strided counters) AND bucket scatter; W frag
// swizzle folded in (order within bucket arbitrary).
__global__ void k_count_scatter(const int* __restrict__ src, const int* __restrict__ dst,
                                int* __restrict__ cnt, int* __restrict__ col,
                                const float* __restrict__ W1, const float* __restrict__ W2,
                                unsigned short* __restrict__ w1f, unsigned short* __restrict__ w2f,
                                int e) {
    int i = blockIdx.x * blockDim.x + threadIdx.x;
    if (i < 2 * DFEAT * DFEAT) {  // W fragment swizzle (B-operand layout)
        int which = i >> 14;
        int idx = i & 16383;
        int k = idx >> 7, nn = idx & 127;
        int f = ((nn >> 4) << 2) + (k >> 5);
        int lane = (nn & 15) | (((k >> 3) & 3) << 4);
        int j = k & 7;
        int o = f * 512 + lane * 8 + j;
        if (which == 0) w1f[o] = f2bf(W1[idx]);
        else            w2f[o] = f2bf(W2[idx]);
    }
    if (i >= e) return;
    int d = dst[i];
    int p = atomicAdd(&cnt[d * CSTR], 1);  // strided: 1 line/counter
    if (p < CAP) col[d * CAP + p] = src[i];
}

// (a) xb = bf16(x * dinv) for i < n*32; zero row at node n (sentinel target).
// (b) pad bucket tail of node i to multiple of 8 with sentinel index n.
__global__ void k_prep(const float* __restrict__ x, const int* __restrict__ cnt,
                       unsigned int* __restrict__ xb2, int* __restrict__ col, int n) {
    int i = blockIdx.x * blockDim.x + threadIdx.x;
    if (i < n * 32) {
        float di = rsqrtf((float)(cnt[(i >> 5) * CSTR] + 1));  // +1 self-loop
        float4 v = ((const float4*)x)[i];
        xb2[i * 2]     = pack2(v.x * di, v.y * di);
        xb2[i * 2 + 1] = pack2(v.z * di, v.w * di);
    } else if (i < (n + 1) * 32) {  // zero row xb[n]
        xb2[i * 2] = 0u;
        xb2[i * 2 + 1] = 0u;
    }
    if (i < n) {  // pad bucket tail to multiple of 8 with sentinel n
        int d = min(cnt[i * CSTR], CAP);
        int dpad = (d + 7) & ~7;
        for (int p = d; p < dpad; ++p) col[i * CAP + p] = n;
    }
}

// Fused: per-block aggregation of BROWS nodes into LDS, then
// GEMM1(+bias+tanh) -> LDS -> GEMM2(+bias) -> fp32 out.
// Gather: 2 passes x (16 nodes x 16 lanes), uint4 gathers, 2-quad unroll
// (8 rows in flight); buckets sentinel-padded to 8 -> uniform inner body.
// GEMM: wave w = (strip=w>>1) x (colh=w&1); A[m=lane&15][k=(lane>>4)*8+j];
// D: col=lane&15, row=(lane>>4)*4+reg (m89-verified layouts).
__global__ __launch_bounds__(256) void k_agg_gemm(
    const uint4* __restrict__ xb4, const int* __restrict__ cnt,
    const int* __restrict__ col,
    const unsigned short* __restrict__ w1f, const float* __restrict__ b1,
    const unsigned short* __restrict__ w2f, const float* __restrict__ b2,
    float* __restrict__ out, int n) {
    __shared__ unsigned short aggs[BROWS * 136];  // 8.7 KB, 136-pitch
    __shared__ unsigned short hs[BROWS * 136];    // 8.7 KB
    const int t = threadIdx.x;

    // ---- aggregation phase ----
    const int lane16 = t & 15;
    const int sub = t >> 4;  // 0..15
    for (int g = 0; g < BROWS / 16; ++g) {
        int node_local = g * 16 + sub;
        int node = blockIdx.x * BROWS + node_local;
        int nodec = min(node, n - 1);
        int raw = cnt[nodec * CSTR];
        int deg = min(raw, CAP);
        float di = rsqrtf((float)(raw + 1));  // bitwise-matches prep's dinv
        uint4 v = xb4[(size_t)nodec * 16 + lane16];  // self term (dinv folded)
        float a0 = bflo(v.x), a1 = bfhi(v.x), a2 = bflo(v.y), a3 = bfhi(v.y);
        float a4 = bflo(v.z), a5 = bfhi(v.z), a6 = bflo(v.w), a7 = bfhi(v.w);
        const int4* col4 = (const int4*)(col + (size_t)nodec * CAP);
        int nq2 = (deg + 7) >> 3;  // 2 quads/iter; tails sentinel-padded to 8
        for (int q = 0; q < nq2; ++q) {
            int4 sa = col4[2 * q];
            int4 sb = col4[2 * q + 1];
            uint4 u0 = xb4[(size_t)sa.x * 16 + lane16];
            uint4 u1 = xb4[(size_t)sa.y * 16 + lane16];
            uint4 u2 = xb4[(size_t)sa.z * 16 + lane16];
            uint4 u3 = xb4[(size_t)sa.w * 16 + lane16];
            uint4 u4 = xb4[(size_t)sb.x * 16 + lane16];
            uint4 u5 = xb4[(size_t)sb.y * 16 + lane16];
            uint4 u6 = xb4[(size_t)sb.z * 16 + lane16];
            uint4 u7 = xb4[(size_t)sb.w * 16 + lane16];
            a0 += bflo(u0.x); a1 += bfhi(u0.x); a2 += bflo(u0.y); a3 += bfhi(u0.y);
            a4 += bflo(u0.z); a5 += bfhi(u0.z); a6 += bflo(u0.w); a7 += bfhi(u0.w);
            a0 += bflo(u1.x); a1 += bfhi(u1.x); a2 += bflo(u1.y); a3 += bfhi(u1.y);
            a4 += bflo(u1.z); a5 += bfhi(u1.z); a6 += bflo(u1.w); a7 += bfhi(u1.w);
            a0 += bflo(u2.x); a1 += bfhi(u2.x); a2 += bflo(u2.y); a3 += bfhi(u2.y);
            a4 += bflo(u2.z); a5 += bfhi(u2.z); a6 += bflo(u2.w); a7 += bfhi(u2.w);
            a0 += bflo(u3.x); a1 += bfhi(u3.x); a2 += bflo(u3.y); a3 += bfhi(u3.y);
            a4 += bflo(u3.z); a5 += bfhi(u3.z); a6 += bflo(u3.w); a7 += bfhi(u3.w);
            a0 += bflo(u4.x); a1 += bfhi(u4.x); a2 += bflo(u4.y); a3 += bfhi(u4.y);
            a4 += bflo(u4.z); a5 += bfhi(u4.z); a6 += bflo(u4.w); a7 += bfhi(u4.w);
            a0 += bflo(u5.x); a1 += bfhi(u5.x); a2 += bflo(u5.y); a3 += bfhi(u5.y);
            a4 += bflo(u5.z); a5 += bfhi(u5.z); a6 += bflo(u5.w); a7 += bfhi(u5.w);
            a0 += bflo(u6.x); a1 += bfhi(u6.x); a2 += bflo(u6.y); a3 += bfhi(u6.y);
            a4 += bflo(u6.z); a5 += bfhi(u6.z); a6 += bflo(u6.w); a7 += bfhi(u6.w);
            a0 += bflo(u7.x); a1 += bfhi(u7.x); a2 += bflo(u7.y); a3 += bfhi(u7.y);
            a4 += bflo(u7.z); a5 += bfhi(u7.z); a6 += bflo(u7.w); a7 += bfhi(u7.w);
        }
        uint4 o;
        o.x = pack2(a0 * di, a1 * di);
        o.y = pack2(a2 * di, a3 * di);
        o.z = pack2(a4 * di, a5 * di);
        o.w = pack2(a6 * di, a7 * di);
        *(uint4*)&aggs[node_local * 136 + lane16 * 8] = o;  // 16 B LDS store
    }
    __syncthreads();

    // ---- GEMM phase: wave -> (row strip, col half) ----
    const int wave = t >> 6, l = t & 63;
    const int strip = wave >> 1;   // 0/1: rows strip*16 .. +15
    const int colh = wave & 1;     // 0/1: cols colh*64 .. +63
    const int kq = l >> 4;
    const int lc = l & 15;
    const int row_local = strip * 16 + lc;

    float4v acc[4];
    for (int ct = 0; ct < 4; ++ct) acc[ct] = (float4v){0.f, 0.f, 0.f, 0.f};
    for (int kc = 0; kc < 4; ++kc) {
        short8 a = *(const short8*)(aggs + row_local * 136 + kc * 32 + kq * 8);
        for (int ct = 0; ct < 4; ++ct) {
            int ctg = colh * 4 + ct;
            short8 b = *(const short8*)(w1f + (ctg * 4 + kc) * 512 + l * 8);
            acc[ct] = __builtin_amdgcn_mfma_f32_16x16x32_bf16(a, b, acc[ct], 0, 0, 0);
        }
    }
    const int drow0 = strip * 16 + kq * 4;
    for (int ct = 0; ct < 4; ++ct) {
        int c = colh * 64 + ct * 16 + lc;
        float bb = b1[c];
        for (int r = 0; r < 4; ++r) {
            float v = fast_tanh(acc[ct][r] + bb);
            hs[(drow0 + r) * 136 + c] = f2bf(v);
        }
    }
    __syncthreads();

    float4v acc2[4];
    for (int ct = 0; ct < 4; ++ct) acc2[ct] = (float4v){0.f, 0.f, 0.f, 0.f};
    for (int kc = 0; kc < 4; ++kc) {
        short8 a = *(const short8*)(hs + row_local * 136 + kc * 32 + kq * 8);
        for (int ct = 0; ct < 4; ++ct) {
            int ctg = colh * 4 + ct;
            short8 b = *(const short8*)(w2f + (ctg * 4 + kc) * 512 + l * 8);
            acc2[ct] = __builtin_amdgcn_mfma_f32_16x16x32_bf16(a, b, acc2[ct], 0, 0, 0);
        }
    }
    const int orow0 = blockIdx.x * BROWS + drow0;
    for (int ct = 0; ct < 4; ++ct) {
        int c = colh * 64 + ct * 16 + lc;
        float bb = b2[c];
        for (int r = 0; r < 4; ++r) {
            int orow = orow0 + r;
            if (orow < n) out[(size_t)orow * DFEAT + c] = acc2[ct][r] + bb;
        }
    }
}

static inline size_t align256(size_t v) { return (v + 255) & ~(size_t)255; }

extern "C" void kernel_launch(void* const* d_in, const int* in_sizes, int n_in,
                              void* d_out, int out_size, void* d_ws, size_t ws_size,
                              hipStream_t stream) {
    const float* x  = (const float*)d_in[0];
    const int*   ei = (const int*)d_in[1];
    const float* W1 = (const float*)d_in[2];
    const float* b1 = (const float*)d_in[3];
    const float* W2 = (const float*)d_in[4];
    const float* b2 = (const float*)d_in[5];
    float* out = (float*)d_out;

    const int N = in_sizes[0] / DFEAT;   // 50000
    const int E = in_sizes[1] / 2;       // 640000
    const int* src = ei;
    const int* dst = ei + E;

    char* ws = (char*)d_ws;
    size_t off = 0;
    int* cnt = (int*)(ws + off);  off += align256((size_t)N * CSTR * 4);
    int* col = (int*)(ws + off);  off += align256((size_t)N * CAP * 4);
    unsigned short* xb  = (unsigned short*)(ws + off); off += align256((size_t)(N + 1) * DFEAT * 2);
    unsigned short* w1f = (unsigned short*)(ws + off); off += align256((size_t)DFEAT * DFEAT * 2);
    unsigned short* w2f = (unsigned short*)(ws + off); off += align256((size_t)DFEAT * DFEAT * 2);

    int t1 = E > 2 * DFEAT * DFEAT ? E : 2 * DFEAT * DFEAT;

    hipMemsetAsync(cnt, 0, (size_t)N * CSTR * 4, stream);
    k_count_scatter<<<(t1 + 255) / 256, 256, 0, stream>>>(
        src, dst, cnt, col, W1, W2, w1f, w2f, E);
    k_prep<<<((N + 1) * 32 + 255) / 256, 256, 0, stream>>>(
        x, cnt, (unsigned int*)xb, col, N);
    k_agg_gemm<<<(N + BROWS - 1) / BROWS, 256, 0, stream>>>(
        (const uint4*)xb, cnt, col, w1f, b1, w2f, b2, out, N);
}

// Round 8
// 154.996 us; speedup vs baseline: 1.1078x; 1.0470x over previous
//
#include <hip/hip_runtime.h>

// GCN 2-layer. out = tanh((Â x) W1 + b1) W2 + b2, with Â(xW1)=(Âx)W1.
// Round 19: R18 with BROWS 32->16. Agg is latency-bound (VALUBusy 23%, FETCH
// 70MB@2.1TB/s, occ 39%); grid 1563 = 6.1 blk/CU left the 8-blk/32-wave cap
// unfilled + long tail. 3125 blocks saturate it. GEMM tile 16x128 (4 waves =
// 4 col-groups), LDS 8.7KB. All else identical to R18.
// 4 nodes: memset | count_scatter(+W) | prep | agg_gemm.
// ws: cnt(3.2MB strided) | col(9.6MB) | xb(12.8MB,+1 zero row) | w1f | w2f

#define DFEAT 128
#define CAP 48       // bucket capacity per node (mult of 8, int4-aligned)
#define CSTR 16      // cnt stride in ints (64 B = one line per node)
#define BROWS 16     // nodes per block

typedef __attribute__((ext_vector_type(8))) short short8;
typedef __attribute__((ext_vector_type(4))) float float4v;

__device__ __forceinline__ float bflo(unsigned int u) {
    union { unsigned int i; float f; } v; v.i = u << 16; return v.f;
}
__device__ __forceinline__ float bfhi(unsigned int u) {
    union { unsigned int i; float f; } v; v.i = u & 0xffff0000u; return v.f;
}
__device__ __forceinline__ unsigned short f2bf(float f) {
    union { unsigned int i; float f; } v; v.f = f;
    unsigned int r = v.i + 0x7fffu + ((v.i >> 16) & 1u);  // RNE
    return (unsigned short)(r >> 16);
}
__device__ __forceinline__ unsigned int pack2(float a, float b) {
    return (unsigned int)f2bf(a) | ((unsigned int)f2bf(b) << 16);
}
// tanh(x) = 1 - 2/(exp(2x)+1); exact at +-inf.
__device__ __forceinline__ float fast_tanh(float x) {
    float e = __expf(2.0f * x);
    float r = __builtin_amdgcn_rcpf(e + 1.0f);  // raw v_rcp_f32, ~1 ulp
    return __builtin_fmaf(-2.0f, r, 1.0f);
}

// One pass: in-degree count (strided counters) AND bucket scatter; W frag
// swizzle folded in (order within bucket arbitrary).
__global__ void k_count_scatter(const int* __restrict__ src, const int* __restrict__ dst,
                                int* __restrict__ cnt, int* __restrict__ col,
                                const float* __restrict__ W1, const float* __restrict__ W2,
                                unsigned short* __restrict__ w1f, unsigned short* __restrict__ w2f,
                                int e) {
    int i = blockIdx.x * blockDim.x + threadIdx.x;
    if (i < 2 * DFEAT * DFEAT) {  // W fragment swizzle (B-operand layout)
        int which = i >> 14;
        int idx = i & 16383;
        int k = idx >> 7, nn = idx & 127;
        int f = ((nn >> 4) << 2) + (k >> 5);
        int lane = (nn & 15) | (((k >> 3) & 3) << 4);
        int j = k & 7;
        int o = f * 512 + lane * 8 + j;
        if (which == 0) w1f[o] = f2bf(W1[idx]);
        else            w2f[o] = f2bf(W2[idx]);
    }
    if (i >= e) return;
    int d = dst[i];
    int p = atomicAdd(&cnt[d * CSTR], 1);  // strided: 1 line/counter
    if (p < CAP) col[d * CAP + p] = src[i];
}

// (a) xb = bf16(x * dinv) for i < n*32; zero row at node n (sentinel target).
// (b) pad bucket tail of node i to multiple of 8 with sentinel index n.
__global__ void k_prep(const float* __restrict__ x, const int* __restrict__ cnt,
                       unsigned int* __restrict__ xb2, int* __restrict__ col, int n) {
    int i = blockIdx.x * blockDim.x + threadIdx.x;
    if (i < n * 32) {
        float di = rsqrtf((float)(cnt[(i >> 5) * CSTR] + 1));  // +1 self-loop
        float4 v = ((const float4*)x)[i];
        xb2[i * 2]     = pack2(v.x * di, v.y * di);
        xb2[i * 2 + 1] = pack2(v.z * di, v.w * di);
    } else if (i < (n + 1) * 32) {  // zero row xb[n]
        xb2[i * 2] = 0u;
        xb2[i * 2 + 1] = 0u;
    }
    if (i < n) {  // pad bucket tail to multiple of 8 with sentinel n
        int d = min(cnt[i * CSTR], CAP);
        int dpad = (d + 7) & ~7;
        for (int p = d; p < dpad; ++p) col[i * CAP + p] = n;
    }
}

// Fused: per-block aggregation of BROWS=16 nodes into LDS, then
// GEMM1(+bias+tanh) -> LDS -> GEMM2(+bias) -> fp32 out.
// Gather: single pass (16 nodes x 16 lanes), uint4 gathers, 2-quad unroll
// (8 rows in flight); buckets sentinel-padded to 8 -> uniform inner body.
// GEMM (16x128 tile): wave w = col-group (32 cols); A[m=lane&15][k=(lane>>4)*8+j];
// D: col=lane&15, row=(lane>>4)*4+reg (m89-verified layouts).
__global__ __launch_bounds__(256, 8) void k_agg_gemm(
    const uint4* __restrict__ xb4, const int* __restrict__ cnt,
    const int* __restrict__ col,
    const unsigned short* __restrict__ w1f, const float* __restrict__ b1,
    const unsigned short* __restrict__ w2f, const float* __restrict__ b2,
    float* __restrict__ out, int n) {
    __shared__ unsigned short aggs[BROWS * 136];  // 4.35 KB, 136-pitch
    __shared__ unsigned short hs[BROWS * 136];    // 4.35 KB
    const int t = threadIdx.x;

    // ---- aggregation phase: one node per 16-lane group ----
    const int lane16 = t & 15;
    const int sub = t >> 4;  // 0..15 = node_local
    {
        int node = blockIdx.x * BROWS + sub;
        int nodec = min(node, n - 1);
        int raw = cnt[nodec * CSTR];
        int deg = min(raw, CAP);
        float di = rsqrtf((float)(raw + 1));  // bitwise-matches prep's dinv
        uint4 v = xb4[(size_t)nodec * 16 + lane16];  // self term (dinv folded)
        float a0 = bflo(v.x), a1 = bfhi(v.x), a2 = bflo(v.y), a3 = bfhi(v.y);
        float a4 = bflo(v.z), a5 = bfhi(v.z), a6 = bflo(v.w), a7 = bfhi(v.w);
        const int4* col4 = (const int4*)(col + (size_t)nodec * CAP);
        int nq2 = (deg + 7) >> 3;  // 2 quads/iter; tails sentinel-padded to 8
        for (int q = 0; q < nq2; ++q) {
            int4 sa = col4[2 * q];
            int4 sb = col4[2 * q + 1];
            uint4 u0 = xb4[(size_t)sa.x * 16 + lane16];
            uint4 u1 = xb4[(size_t)sa.y * 16 + lane16];
            uint4 u2 = xb4[(size_t)sa.z * 16 + lane16];
            uint4 u3 = xb4[(size_t)sa.w * 16 + lane16];
            uint4 u4 = xb4[(size_t)sb.x * 16 + lane16];
            uint4 u5 = xb4[(size_t)sb.y * 16 + lane16];
            uint4 u6 = xb4[(size_t)sb.z * 16 + lane16];
            uint4 u7 = xb4[(size_t)sb.w * 16 + lane16];
            a0 += bflo(u0.x); a1 += bfhi(u0.x); a2 += bflo(u0.y); a3 += bfhi(u0.y);
            a4 += bflo(u0.z); a5 += bfhi(u0.z); a6 += bflo(u0.w); a7 += bfhi(u0.w);
            a0 += bflo(u1.x); a1 += bfhi(u1.x); a2 += bflo(u1.y); a3 += bfhi(u1.y);
            a4 += bflo(u1.z); a5 += bfhi(u1.z); a6 += bflo(u1.w); a7 += bfhi(u1.w);
            a0 += bflo(u2.x); a1 += bfhi(u2.x); a2 += bflo(u2.y); a3 += bfhi(u2.y);
            a4 += bflo(u2.z); a5 += bfhi(u2.z); a6 += bflo(u2.w); a7 += bfhi(u2.w);
            a0 += bflo(u3.x); a1 += bfhi(u3.x); a2 += bflo(u3.y); a3 += bfhi(u3.y);
            a4 += bflo(u3.z); a5 += bfhi(u3.z); a6 += bflo(u3.w); a7 += bfhi(u3.w);
            a0 += bflo(u4.x); a1 += bfhi(u4.x); a2 += bflo(u4.y); a3 += bfhi(u4.y);
            a4 += bflo(u4.z); a5 += bfhi(u4.z); a6 += bflo(u4.w); a7 += bfhi(u4.w);
            a0 += bflo(u5.x); a1 += bfhi(u5.x); a2 += bflo(u5.y); a3 += bfhi(u5.y);
            a4 += bflo(u5.z); a5 += bfhi(u5.z); a6 += bflo(u5.w); a7 += bfhi(u5.w);
            a0 += bflo(u6.x); a1 += bfhi(u6.x); a2 += bflo(u6.y); a3 += bfhi(u6.y);
            a4 += bflo(u6.z); a5 += bfhi(u6.z); a6 += bflo(u6.w); a7 += bfhi(u6.w);
            a0 += bflo(u7.x); a1 += bfhi(u7.x); a2 += bflo(u7.y); a3 += bfhi(u7.y);
            a4 += bflo(u7.z); a5 += bfhi(u7.z); a6 += bflo(u7.w); a7 += bfhi(u7.w);
        }
        uint4 o;
        o.x = pack2(a0 * di, a1 * di);
        o.y = pack2(a2 * di, a3 * di);
        o.z = pack2(a4 * di, a5 * di);
        o.w = pack2(a6 * di, a7 * di);
        *(uint4*)&aggs[sub * 136 + lane16 * 8] = o;  // 16 B LDS store
    }
    __syncthreads();

    // ---- GEMM phase: wave -> 32-col group of the 16x128 tile ----
    const int wave = t >> 6, l = t & 63;
    const int kq = l >> 4;
    const int lc = l & 15;

    float4v acc[2];
    for (int ct = 0; ct < 2; ++ct) acc[ct] = (float4v){0.f, 0.f, 0.f, 0.f};
    for (int kc = 0; kc < 4; ++kc) {
        short8 a = *(const short8*)(aggs + lc * 136 + kc * 32 + kq * 8);
        for (int ct = 0; ct < 2; ++ct) {
            int ctg = wave * 2 + ct;
            short8 b = *(const short8*)(w1f + (ctg * 4 + kc) * 512 + l * 8);
            acc[ct] = __builtin_amdgcn_mfma_f32_16x16x32_bf16(a, b, acc[ct], 0, 0, 0);
        }
    }
    const int drow0 = kq * 4;
    for (int ct = 0; ct < 2; ++ct) {
        int c = wave * 32 + ct * 16 + lc;
        float bb = b1[c];
        for (int r = 0; r < 4; ++r) {
            float v = fast_tanh(acc[ct][r] + bb);
            hs[(drow0 + r) * 136 + c] = f2bf(v);
        }
    }
    __syncthreads();

    float4v acc2[2];
    for (int ct = 0; ct < 2; ++ct) acc2[ct] = (float4v){0.f, 0.f, 0.f, 0.f};
    for (int kc = 0; kc < 4; ++kc) {
        short8 a = *(const short8*)(hs + lc * 136 + kc * 32 + kq * 8);
        for (int ct = 0; ct < 2; ++ct) {
            int ctg = wave * 2 + ct;
            short8 b = *(const short8*)(w2f + (ctg * 4 + kc) * 512 + l * 8);
            acc2[ct] = __builtin_amdgcn_mfma_f32_16x16x32_bf16(a, b, acc2[ct], 0, 0, 0);
        }
    }
    const int orow0 = blockIdx.x * BROWS + drow0;
    for (int ct = 0; ct < 2; ++ct) {
        int c = wave * 32 + ct * 16 + lc;
        float bb = b2[c];
        for (int r = 0; r < 4; ++r) {
            int orow = orow0 + r;
            if (orow < n) out[(size_t)orow * DFEAT + c] = acc2[ct][r] + bb;
        }
    }
}

static inline size_t align256(size_t v) { return (v + 255) & ~(size_t)255; }

extern "C" void kernel_launch(void* const* d_in, const int* in_sizes, int n_in,
                              void* d_out, int out_size, void* d_ws, size_t ws_size,
                              hipStream_t stream) {
    const float* x  = (const float*)d_in[0];
    const int*   ei = (const int*)d_in[1];
    const float* W1 = (const float*)d_in[2];
    const float* b1 = (const float*)d_in[3];
    const float* W2 = (const float*)d_in[4];
    const float* b2 = (const float*)d_in[5];
    float* out = (float*)d_out;

    const int N = in_sizes[0] / DFEAT;   // 50000
    const int E = in_sizes[1] / 2;       // 640000
    const int* src = ei;
    const int* dst = ei + E;

    char* ws = (char*)d_ws;
    size_t off = 0;
    int* cnt = (int*)(ws + off);  off += align256((size_t)N * CSTR * 4);
    int* col = (int*)(ws + off);  off += align256((size_t)N * CAP * 4);
    unsigned short* xb  = (unsigned short*)(ws + off); off += align256((size_t)(N + 1) * DFEAT * 2);
    unsigned short* w1f = (unsigned short*)(ws + off); off += align256((size_t)DFEAT * DFEAT * 2);
    unsigned short* w2f = (unsigned short*)(ws + off); off += align256((size_t)DFEAT * DFEAT * 2);

    int t1 = E > 2 * DFEAT * DFEAT ? E : 2 * DFEAT * DFEAT;

    hipMemsetAsync(cnt, 0, (size_t)N * CSTR * 4, stream);
    k_count_scatter<<<(t1 + 255) / 256, 256, 0, stream>>>(
        src, dst, cnt, col, W1, W2, w1f, w2f, E);
    k_prep<<<((N + 1) * 32 + 255) / 256, 256, 0, stream>>>(
        x, cnt, (unsigned int*)xb, col, N);
    k_agg_gemm<<<(N + BROWS - 1) / BROWS, 256, 0, stream>>>(
        (const uint4*)xb, cnt, col, w1f, b1, w2f, b2, out, N);
}